// Round 6
// baseline (109.958 us; speedup 1.0000x reference)
//
#include <hip/hip_runtime.h>

#define TC 256
#define DEMB 384
#define VOC 100
#define VK 128       // padded vocab (K dim for MFMA)
#define MST 136      // M LDS row stride in elems (272 B: 16B-aligned, 2 lanes/bank)
#define WIN 96
#define TTILE 32
#define LOG_SQRT_2PI 0.9189385332046727f

typedef short v8s __attribute__((ext_vector_type(8)));
typedef float v4f __attribute__((ext_vector_type(4)));

__device__ __forceinline__ unsigned short f32_to_bf16_rne(float f) {
    union { float f; unsigned int u; } x; x.f = f;
    unsigned int u = x.u;
    return (unsigned short)((u + 0x7FFFu + ((u >> 16) & 1u)) >> 16);
}

// Fused pre-pass (text-independent EBT + per-b scan/params).
// Blocks [0,192):  EBT[n][v] = bf16(embed[v][n]) (v<100, else 0); [384][128] bf16
// Blocks [192,224): per-b scan of durs -> per-char params + per-tile j0 + totdur
__global__ __launch_bounds__(256) void prep_kernel(
    const int* __restrict__ text, const int* __restrict__ durs,
    const float* __restrict__ embed,
    unsigned short* __restrict__ EBT,
    float* __restrict__ ctrA, float* __restrict__ isgA, float* __restrict__ lgA,
    int* __restrict__ j0A, int* __restrict__ totA)
{
    if (blockIdx.x < 192) {
        int i = blockIdx.x * 256 + threadIdx.x;   // i < 49152
        int v = i & (VK - 1);
        int n = i >> 7;
        float val = (v < VOC) ? embed[v * DEMB + n] : 0.0f;
        EBT[i] = f32_to_bf16_rne(val);
    } else {
        const int b = blockIdx.x - 192;
        const int c = threadIdx.x;
        const int lane = c & 63, wv = c >> 6;
        int d = durs[b * TC + c];
        // exact int inclusive scan: wave shuffle + LDS wave-sum combine
        int x = d;
#pragma unroll
        for (int ofs = 1; ofs < 64; ofs <<= 1) {
            int n = __shfl_up(x, ofs, 64);
            if (lane >= ofs) x += n;
        }
        __shared__ int s_wsum[4];
        if (lane == 63) s_wsum[wv] = x;
        __syncthreads();
        int pre = 0;
        for (int k = 0; k < wv; ++k) pre += s_wsum[k];
        int en = pre + x;
        int st = en - d;
        if (c == TC - 1) totA[b] = en;

        float df  = (float)d;
        float sig = df * 0.5f + 1e-6f;           // dur/SIGMA_C + EPS
        ctrA[b * TC + c] = (float)st + df * 0.5f;
        isgA[b * TC + c] = 1.0f / sig;
        lgA[b * TC + c]  = -logf(sig) - LOG_SQRT_2PI;

        // tiles whose first frame lies in [st, en): this char is j0
        for (int t0 = ((st + 31) >> 5) << 5; t0 < en; t0 += 32)
            j0A[b * 64 + (t0 >> 5)] = c;
    }
}

__global__ __launch_bounds__(256, 2) void gauss_embed_mfma_kernel(
    const float* __restrict__ embed,          // [100,384] fp32 (pad rows)
    const int* __restrict__ text,             // [32,256]
    const unsigned short* __restrict__ EBT,   // [384][128] bf16 (clean, tiny)
    const float* __restrict__ ctrA, const float* __restrict__ isgA,
    const float* __restrict__ lgA,
    const int* __restrict__ j0A, const int* __restrict__ totA,
    float* __restrict__ out, int Tt)
{
    const int b   = blockIdx.y;
    const int t0  = blockIdx.x * TTILE;
    const int tid = threadIdx.x;
    const int totdur = totA[b];

    // ---- pure pad tile: every row = embed[0][:] ----
    if (t0 >= totdur) {
        const float4* e0 = (const float4*)embed;   // row 0 (PAD)
        int row = tid >> 3, q4 = tid & 7;
        int t = t0 + row;
        if (t < Tt) {
            float4* orow = (float4*)(out + (size_t)(b * Tt + t) * DEMB);
#pragma unroll
            for (int k = 0; k < 12; ++k) orow[q4 + 8 * k] = e0[q4 + 8 * k];
        }
        return;
    }

    const int wv   = tid >> 6;    // wave: n-cols [wv*96, wv*96+96)
    const int lane = tid & 63;
    const int nq   = lane & 15;
    const int q    = lane >> 4;

    __shared__ float s_Mf[TTILE * MST];                          // 17408 B
    __shared__ __align__(16) unsigned short s_M[TTILE * MST];    //  8704 B
    __shared__ float s_ctr[WIN], s_isg[WIN], s_A[WIN];
    __shared__ int   s_wtx[WIN];
    __shared__ float s_part[256];
    __shared__ float s_invS[TTILE];

    int j0 = j0A[b * 64 + (t0 >> 5)];
    int base = j0 - 31;
    base = base < 0 ? 0 : base;
    if (base > TC - WIN) base = TC - WIN;

    // zero the histogram; stage params + window text
    for (int i = tid; i < TTILE * MST; i += 256) s_Mf[i] = 0.0f;
    if (tid < WIN) {
        s_ctr[tid] = ctrA[b * TC + base + tid];
        s_isg[tid] = isgA[b * TC + base + tid];
        s_A[tid]   = lgA[b * TC + base + tid];
        s_wtx[tid] = text[b * TC + base + tid];
    }
    __syncthreads();

    // ---- phase 1: scatter gaussian weights into vocab histogram ----
    {
        const int t = tid & 31;
        const int g = tid >> 5;
        const float tf = (float)(t0 + t) + 0.5f;
        float lsum = 0.0f;
#pragma unroll
        for (int cc = 0; cc < 12; ++cc) {
            int c = g * 12 + cc;
            float z = (tf - s_ctr[c]) * s_isg[c];
            float w = __expf(fmaf(-0.5f * z, z, s_A[c]));
            lsum += w;
            atomicAdd(&s_Mf[t * MST + s_wtx[c]], w);
        }
        s_part[tid] = lsum;
    }
    __syncthreads();

    // ---- normalizers + bf16 convert of M ----
    if (tid < TTILE) {
        float s = 1e-6f;
#pragma unroll
        for (int g = 0; g < 8; ++g) s += s_part[g * 32 + tid];
        s_invS[tid] = 1.0f / s;
    }
    for (int i = tid; i < TTILE * VK; i += 256) {
        int t = i >> 7, k = i & (VK - 1);
        s_M[t * MST + k] = f32_to_bf16_rne(s_Mf[t * MST + k]);
    }
    __syncthreads();

    // ---- phase 2: D[32x384] = M[32x128] x EBT^T[128x384] via MFMA ----
    v4f acc[6][2];
#pragma unroll
    for (int nt = 0; nt < 6; ++nt)
#pragma unroll
        for (int mt = 0; mt < 2; ++mt) {
            v4f z = {0.0f, 0.0f, 0.0f, 0.0f};
            acc[nt][mt] = z;
        }

#pragma unroll
    for (int ks = 0; ks < 4; ++ks) {
        const int k0 = ks * 32 + q * 8;
        v8s a0 = *(const v8s*)(s_M + nq * MST + k0);
        v8s a1 = *(const v8s*)(s_M + (16 + nq) * MST + k0);
#pragma unroll
        for (int nt = 0; nt < 6; ++nt) {
            // B-frag: B[k=v][n=nq] = EBT[n][v] — contiguous 16 B, aligned
            v8s bf = *(const v8s*)(EBT + (wv * 96 + nt * 16 + nq) * VK + k0);
            acc[nt][0] = __builtin_amdgcn_mfma_f32_16x16x32_bf16(a0, bf, acc[nt][0], 0, 0, 0);
            acc[nt][1] = __builtin_amdgcn_mfma_f32_16x16x32_bf16(a1, bf, acc[nt][1], 0, 0, 0);
        }
    }

    // ---- epilogue: normalize, pad rows -> embed[0], store ----
    const bool anypad = (t0 + TTILE > totdur);   // wave-uniform
    float pe[6];
    if (anypad) {
#pragma unroll
        for (int nt = 0; nt < 6; ++nt) pe[nt] = embed[wv * 96 + nt * 16 + nq];
    }

#pragma unroll
    for (int mt = 0; mt < 2; ++mt) {
#pragma unroll
        for (int r = 0; r < 4; ++r) {
            int tl = mt * 16 + q * 4 + r;        // C/D: row = q*4 + reg
            int t = t0 + tl;
            if (t >= Tt) continue;
            float sv = s_invS[tl];
            bool pad = anypad && (t >= totdur);
            float* orow = out + (size_t)(b * Tt + t) * DEMB + wv * 96 + nq;
#pragma unroll
            for (int nt = 0; nt < 6; ++nt) {
                float val = pad ? pe[nt] : acc[nt][mt][r] * sv;
                orow[nt * 16] = val;
            }
        }
    }
}

extern "C" void kernel_launch(void* const* d_in, const int* in_sizes, int n_in,
                              void* d_out, int out_size, void* d_ws, size_t ws_size,
                              hipStream_t stream) {
    const int*   text  = (const int*)d_in[0];
    const int*   durs  = (const int*)d_in[1];
    const float* embed = (const float*)d_in[2];
    float* out = (float*)d_out;

    const int B = 32;
    const int Tt = out_size / (B * DEMB);

    // workspace layout
    char* ws = (char*)d_ws;
    unsigned short* EBT = (unsigned short*)ws;          // 98,304 B
    float* ctrA = (float*)(ws + 98304);                 // 32,768 B
    float* isgA = (float*)(ws + 98304 + 32768);         // 32,768 B
    float* lgA  = (float*)(ws + 98304 + 65536);         // 32,768 B
    int*   j0A  = (int*)  (ws + 98304 + 98304);         //  8,192 B
    int*   totA = (int*)  (ws + 98304 + 106496);        //    128 B

    prep_kernel<<<224, 256, 0, stream>>>(text, durs, embed, EBT,
                                         ctrA, isgA, lgA, j0A, totA);

    dim3 grid((Tt + TTILE - 1) / TTILE, B);
    gauss_embed_mfma_kernel<<<grid, 256, 0, stream>>>(embed, text, EBT,
                                                      ctrA, isgA, lgA,
                                                      j0A, totA, out, Tt);
}

// Round 7
// 102.000 us; speedup vs baseline: 1.0780x; 1.0780x over previous
//
#include <hip/hip_runtime.h>

#define TC 256
#define DEMB 384
#define VOC 100
#define WIN 96
#define TTILE 32
#define WPS 104      // W' LDS row stride in bf16 elems (16B-aligned rows)
#define CST 288      // ET c-stride in elems (576 B rows; 16B-aligned window reads)
#define OST 404      // s_out row stride in floats: 404%32=20 -> 2-way banks; 16B aligned
#define LOG_SQRT_2PI 0.9189385332046727f

typedef short v8s __attribute__((ext_vector_type(8)));
typedef float v4f __attribute__((ext_vector_type(4)));

__device__ __forceinline__ unsigned short f32_to_bf16_rne(float f) {
    union { float f; unsigned int u; } x; x.f = f;
    unsigned int u = x.u;
    return (unsigned short)((u + 0x7FFFu + ((u >> 16) & 1u)) >> 16);
}

// Fused pre-pass.
// Blocks [0,576): ET[b][n][c] = bf16(embed[text[b][c]][n]); thread=(b,nseg24,c)
// Blocks [576,608): per-b scan of durs -> per-char params + per-tile j0 + totdur
__global__ __launch_bounds__(256) void prep_kernel(
    const int* __restrict__ text, const int* __restrict__ durs,
    const float* __restrict__ embed,
    unsigned short* __restrict__ ET,
    float* __restrict__ ctrA, float* __restrict__ isgA, float* __restrict__ lgA,
    int* __restrict__ j0A, int* __restrict__ totA)
{
    if (blockIdx.x < 576) {
        int i = blockIdx.x * 256 + threadIdx.x;
        int c = i % CST;
        int r = i / CST;            // b*16 + nseg
        int nseg = r & 15;
        int b = r >> 4;
        if (c >= TC) return;
        int v = text[b * TC + c];
        const float* erow = embed + (size_t)v * DEMB + nseg * 24;
        unsigned short* dst = ET + ((size_t)b * DEMB + nseg * 24) * CST + c;
#pragma unroll
        for (int k = 0; k < 6; ++k) {
            float4 e = *(const float4*)(erow + 4 * k);
            dst[(4 * k + 0) * CST] = f32_to_bf16_rne(e.x);
            dst[(4 * k + 1) * CST] = f32_to_bf16_rne(e.y);
            dst[(4 * k + 2) * CST] = f32_to_bf16_rne(e.z);
            dst[(4 * k + 3) * CST] = f32_to_bf16_rne(e.w);
        }
    } else {
        const int b = blockIdx.x - 576;
        const int c = threadIdx.x;
        const int lane = c & 63, wv = c >> 6;
        int d = durs[b * TC + c];
        // exact int inclusive scan: wave shuffle + LDS wave-sum combine
        int x = d;
#pragma unroll
        for (int ofs = 1; ofs < 64; ofs <<= 1) {
            int n = __shfl_up(x, ofs, 64);
            if (lane >= ofs) x += n;
        }
        __shared__ int s_wsum[4];
        if (lane == 63) s_wsum[wv] = x;
        __syncthreads();
        int pre = 0;
        for (int k = 0; k < wv; ++k) pre += s_wsum[k];
        int en = pre + x;
        int st = en - d;
        if (c == TC - 1) totA[b] = en;

        float df  = (float)d;
        float sig = df * 0.5f + 1e-6f;           // dur/SIGMA_C + EPS
        ctrA[b * TC + c] = (float)st + df * 0.5f;
        isgA[b * TC + c] = 1.0f / sig;
        lgA[b * TC + c]  = -logf(sig) - LOG_SQRT_2PI;

        // tiles whose first frame lies in [st, en): this char is j0
        for (int t0 = ((st + 31) >> 5) << 5; t0 < en; t0 += 32)
            j0A[b * 64 + (t0 >> 5)] = c;
    }
}

__global__ __launch_bounds__(256, 2) void gauss_embed_mfma_kernel(
    const float* __restrict__ embed,          // [100,384] fp32 (pad rows)
    const unsigned short* __restrict__ ET,    // [32][384][CST] bf16 gathered
    const float* __restrict__ ctrA, const float* __restrict__ isgA,
    const float* __restrict__ lgA,
    const int* __restrict__ j0A, const int* __restrict__ totA,
    float* __restrict__ out, int Tt)
{
    const int b   = blockIdx.y;
    const int t0  = blockIdx.x * TTILE;
    const int tid = threadIdx.x;
    const int totdur = totA[b];

    // ---- pure pad tile: every row = embed[0][:] ----
    if (t0 >= totdur) {
        const float4* e0 = (const float4*)embed;   // row 0 (PAD)
        int row = tid >> 3, q4 = tid & 7;
        int t = t0 + row;
        if (t < Tt) {
            float4* orow = (float4*)(out + (size_t)(b * Tt + t) * DEMB);
#pragma unroll
            for (int k = 0; k < 12; ++k) orow[q4 + 8 * k] = e0[q4 + 8 * k];
        }
        return;
    }

    const int wv   = tid >> 6;    // wave: n-cols [wv*96, wv*96+96)
    const int lane = tid & 63;
    const int nq   = lane & 15;
    const int q    = lane >> 4;

    __shared__ float s_ctr[WIN], s_isg[WIN], s_A[WIN];
    __shared__ __align__(16) unsigned short s_wp[TTILE * WPS];
    __shared__ float s_part[256];
    __shared__ float s_invS[TTILE];
    __shared__ __align__(16) float s_out[16 * OST];   // 25856 B staging

    int j0 = j0A[b * 64 + (t0 >> 5)];
    int base = j0 - 31;
    base = base < 0 ? 0 : base;
    base &= ~7;                                // 16B-align ET window reads
    if (base > TC - WIN) base = TC - WIN;      // 160 (multiple of 8)

    if (tid < WIN) {
        s_ctr[tid] = ctrA[b * TC + base + tid];
        s_isg[tid] = isgA[b * TC + base + tid];
        s_A[tid]   = lgA[b * TC + base + tid];
    }
    __syncthreads();

    // ---- phase 1: W'[t][c] = bf16(w), partial row sums ----
    {
        const int t = tid & 31;
        const int g = tid >> 5;
        const float tf = (float)(t0 + t) + 0.5f;
        float lsum = 0.0f;
#pragma unroll
        for (int cc = 0; cc < 12; ++cc) {
            int c = g * 12 + cc;
            float z = (tf - s_ctr[c]) * s_isg[c];
            float w = __expf(fmaf(-0.5f * z, z, s_A[c]));
            lsum += w;
            s_wp[t * WPS + c] = f32_to_bf16_rne(w);
        }
        s_part[tid] = lsum;
    }
    __syncthreads();

    if (tid < TTILE) {
        float s = 1e-6f;
#pragma unroll
        for (int g = 0; g < 8; ++g) s += s_part[g * 32 + tid];
        s_invS[tid] = 1.0f / s;
    }
    __syncthreads();

    // ---- phase 2: D[32x384] = W'[32x96] x E'[96x384] via MFMA ----
    const unsigned short* ETb = ET + (size_t)b * DEMB * CST + base;

    v4f acc[6][2];
#pragma unroll
    for (int nt = 0; nt < 6; ++nt)
#pragma unroll
        for (int mt = 0; mt < 2; ++mt) {
            v4f z = {0.0f, 0.0f, 0.0f, 0.0f};
            acc[nt][mt] = z;
        }

#pragma unroll
    for (int ks = 0; ks < 3; ++ks) {
        const int c0 = ks * 32 + q * 8;
        v8s a0 = *(const v8s*)(s_wp + nq * WPS + c0);
        v8s a1 = *(const v8s*)(s_wp + (16 + nq) * WPS + c0);
#pragma unroll
        for (int nt = 0; nt < 6; ++nt) {
            v8s bf = *(const v8s*)(ETb + (size_t)(wv * 96 + nt * 16 + nq) * CST + c0);
            acc[nt][0] = __builtin_amdgcn_mfma_f32_16x16x32_bf16(a0, bf, acc[nt][0], 0, 0, 0);
            acc[nt][1] = __builtin_amdgcn_mfma_f32_16x16x32_bf16(a1, bf, acc[nt][1], 0, 0, 0);
        }
    }

    // ---- epilogue: LDS transpose -> full-line vectorized stores ----
    const float4* e0 = (const float4*)embed;   // row 0 (PAD)
    const int col = wv * 96 + nq;              // + nt*16

#pragma unroll
    for (int mt = 0; mt < 2; ++mt) {
        __syncthreads();   // (mt=1: protect s_out reuse; mt=0: harmless)
        // write raw acc fragments: C/D row = q*4 + r (within half-tile)
#pragma unroll
        for (int nt = 0; nt < 6; ++nt) {
#pragma unroll
            for (int r = 0; r < 4; ++r)
                s_out[(q * 4 + r) * OST + col + nt * 16] = acc[nt][mt][r];
        }
        __syncthreads();
        // row-contiguous read + dwordx4 store (4 rows x 256 B per wave-inst)
        int row = tid >> 4;        // 0..15
        int s   = tid & 15;        // 0..15
        int tl  = mt * 16 + row;
        int t   = t0 + tl;
        if (t < Tt) {
            float sv = s_invS[tl];
            bool pad = (t >= totdur);
            float4* orow = (float4*)(out + (size_t)(b * Tt + t) * DEMB);
#pragma unroll
            for (int k = 0; k < 6; ++k) {
                int c4 = s + 16 * k;               // float4 index 0..95
                float4 v;
                if (pad) {
                    v = e0[c4];
                } else {
                    v = *(const float4*)(&s_out[row * OST + 4 * c4]);
                    v.x *= sv; v.y *= sv; v.z *= sv; v.w *= sv;
                }
                orow[c4] = v;
            }
        }
    }
}

extern "C" void kernel_launch(void* const* d_in, const int* in_sizes, int n_in,
                              void* d_out, int out_size, void* d_ws, size_t ws_size,
                              hipStream_t stream) {
    const int*   text  = (const int*)d_in[0];
    const int*   durs  = (const int*)d_in[1];
    const float* embed = (const float*)d_in[2];
    float* out = (float*)d_out;

    const int B = 32;
    const int Tt = out_size / (B * DEMB);

    // workspace layout
    char* ws = (char*)d_ws;
    unsigned short* ET = (unsigned short*)ws;                   // 7,077,888 B
    float* ctrA = (float*)(ws + 7077888);                       // 32,768 B
    float* isgA = (float*)(ws + 7077888 + 32768);               // 32,768 B
    float* lgA  = (float*)(ws + 7077888 + 65536);               // 32,768 B
    int*   j0A  = (int*)  (ws + 7077888 + 98304);               //  8,192 B
    int*   totA = (int*)  (ws + 7077888 + 106496);              //    128 B

    prep_kernel<<<608, 256, 0, stream>>>(text, durs, embed, ET,
                                         ctrA, isgA, lgA, j0A, totA);

    dim3 grid((Tt + TTILE - 1) / TTILE, B);
    gauss_embed_mfma_kernel<<<grid, 256, 0, stream>>>(embed, ET, ctrA, isgA, lgA,
                                                      j0A, totA, out, Tt);
}